// Round 5
// baseline (1907.895 us; speedup 1.0000x reference)
//
#include <hip/hip_runtime.h>

// DynamicRNNEncoder on MI355X — round 5.
// Persistent cooperative kernel; weights register-resident (f16).
// Cached A-panel loads, sc0sc1 write-through stores, and a HIERARCHICAL
// XCD-aware barrier: local arrive at XCD L2 (workgroup-scope atomics),
// 8 leader adds to one IF counter, single-line sc1 poll.

typedef _Float16 f16;
typedef _Float16 f16x8 __attribute__((ext_vector_type(8)));
typedef float f32x4 __attribute__((ext_vector_type(4)));

#define B_ 64
#define T_ 256
#define H_ 512
#define EN_ 256
#define ET_ 256
#define D_ 256
#define VN_ 300
#define VS_ 100

#define NB_MAIN_ 128   // 4 main units (16 gate rows) each
#define NB_DYN_ 64     // 4 dyn units each
#define NBLK_ 192
#define NTHR_ 256
#define POLL_CAP_ (1u << 22)   // ~112ms guard against pathological deadlock

// ---- barrier counter word indices (64B lines = 16 words) ----
#define IDX_G_     0     // global step counter (sc1-only; reset each launch)
#define IDX_INIT1_ 16    // init barrier 1 (sc1-only; reset)
#define IDX_INIT2_ 32    // init barrier 2 (sc1-only; reset)
#define IDX_XCD_   48    // +x*16: per-XCD block count (sc1-only; reset)
#define IDX_LCL_   256   // +x*16: per-XCD arrive counters (sc0/L2-local; NEVER reset,
                         // monotonic with per-launch base — dirty-line writeback safe)

// ---- workspace layout (bytes) ----
static constexpr size_t OFF_CNT  = 0;                                   // 4KB counter region
static constexpr size_t OFF_EMBN = 4096;                                // embN f16  [300][256]
static constexpr size_t OFF_EMBT = OFF_EMBN + (size_t)VN_ * EN_ * 2;    // embT f16  [100][256]
static constexpr size_t OFF_DINH = OFF_EMBT + (size_t)VS_ * ET_ * 2;    // dyn_init_h f16 [256]
static constexpr size_t OFF_PREV = OFF_DINH + 1024;                     // prev int32 [T][B]
static constexpr size_t OFF_HH   = OFF_PREV + (size_t)T_ * B_ * 4;      // Hhist f16 [T+1][B][H]
static constexpr size_t OFF_HD   = OFF_HH + (size_t)(T_ + 1) * B_ * H_ * 2; // HdHist f16 [T][B][D]
static constexpr size_t OFF_CD   = OFF_HD + (size_t)T_ * B_ * D_ * 2;   // CdHist f32 [T][B][D]
static constexpr size_t WS_NEED  = OFF_CD + (size_t)T_ * B_ * D_ * 4;   // ~42.3 MB

struct RnnParams {
  const int* n_input; const int* t_input; const int* s2d;
  const float* W_ih; const float* W_hh; const float* b_ih; const float* b_hh;
  const float* Wd_ih; const float* Wd_hh; const float* bd_ih; const float* bd_hh;
  const float* cell_init; const float* dyn_init_c;
  const f16* embN16; const f16* embT16; const f16* dynih16;
  const int* prev;
  f16* Hhist; f16* HdHist; float* CdHist;
  float* out; unsigned* cnt;
};

__device__ __forceinline__ float sigm(float x) { return 1.f / (1.f + __expf(-x)); }
__device__ __forceinline__ float tanh_fast(float x) {
  float e = __expf(2.f * x);
  return 1.f - 2.f / (e + 1.f);
}

// ---- coherent-point store helpers (sc0sc1 write-through) ----
__device__ __forceinline__ void cstore8(void* p, unsigned long long v) {
  __hip_atomic_store((unsigned long long*)p, v, __ATOMIC_RELAXED,
                     __HIP_MEMORY_SCOPE_AGENT);
}
__device__ __forceinline__ void cstore16(void* p, f32x4 v) {
  asm volatile("global_store_dwordx4 %0, %1, off sc0 sc1"
               :: "v"(p), "v"(v) : "memory");
}

// ---- setup: f16 conversions, Hhist[0] init, sc1 counter reset ----
__global__ void setup_kernel(const float* embN, const float* embT,
                             const float* hid_init, const float* dyn_init_h,
                             f16* embN16, f16* embT16, f16* dynih16,
                             f16* Hhist0, unsigned* cnt) {
  int i = blockIdx.x * blockDim.x + threadIdx.x;
  if (i < 256)       cnt[i] = 0u;   // sc1-only lines; LCL region (word 256+) untouched
  if (i < VN_ * EN_) embN16[i] = (f16)embN[i];
  if (i < VS_ * ET_) embT16[i] = (f16)embT[i];
  if (i < D_)        dynih16[i] = (f16)dyn_init_h[i];
  if (i < B_ * H_)   Hhist0[i] = (f16)hid_init[i & (H_ - 1)];
  __threadfence();   // flush to coherent point
}

// ---- prev-occurrence table: prev[t][b] = last t'<t with same (dynamic) token ----
__global__ void prev_kernel(const int* t_input, const int* s2d, int* prev) {
  int idx = blockIdx.x * blockDim.x + threadIdx.x;
  if (idx < B_ * T_) {
    int b = idx / T_, t = idx % T_;
    int tt = t_input[b * T_ + t];
    int p = -1;
    if (s2d[tt] != tt) {
      for (int q = t - 1; q >= 0; --q)
        if (t_input[b * T_ + q] == tt) { p = q; break; }
    }
    prev[t * B_ + b] = p;
  }
  __threadfence();
}

__device__ __forceinline__ void resolve(const RnnParams& p, bool isDyn, int t, int b,
                                        const f16** aN, const f16** aX,
                                        const float** aC, int* dynw) {
  const int nt = p.n_input[b * T_ + t];
  aN[b] = p.embN16 + (size_t)nt * EN_;
  const int tt = p.t_input[b * T_ + t];
  const int pv = p.prev[t * B_ + b];
  const f16* hd = (pv >= 0) ? (p.HdHist + ((size_t)pv * B_ + b) * D_) : p.dynih16;
  const int s2 = p.s2d[tt];
  const bool st = (s2 == tt);
  if (!isDyn) {
    aX[b] = st ? (p.embT16 + (size_t)s2 * ET_) : hd;
  } else {
    aX[b] = hd;
    aC[b] = (pv >= 0) ? (p.CdHist + ((size_t)pv * B_ + b) * D_) : p.dyn_init_c;
    dynw[b] = st ? 0 : 1;
  }
}

// ---- main cooperative recurrent kernel ----
__global__ __launch_bounds__(NTHR_, 1) void rnn_main(RnnParams p) {
  const int blk  = blockIdx.x;
  const int tid  = threadIdx.x;
  const int wave = tid >> 6;
  const int lane = tid & 63;
  const bool isDyn = (blk >= NB_MAIN_);
  const int u0 = isDyn ? (blk - NB_MAIN_) * 4 : blk * 4;

  // Entry fence: wbL2 (preserves any dirty LCL counter lines from the previous
  // replay) + invalidate, so cached reads re-fetch from the coherent point.
  __threadfence();

  __shared__ float s_bias[16];
  __shared__ float s_scr[64][17];
  __shared__ const f16*  s_aN[2][64];
  __shared__ const f16*  s_aX[2][64];
  __shared__ const float* s_aC[2][64];
  __shared__ int s_dynw[2][64];

  // ---- hierarchical-barrier init (tid 0 only; values live in its registers) ----
  unsigned xcd = 0, lbase = 0, nloc = 1, nact = 1;
  if (tid == 0) {
    asm volatile("s_getreg_b32 %0, hwreg(HW_REG_XCC_ID)" : "=s"(xcd));
    xcd &= 7u;
    __hip_atomic_fetch_add(&p.cnt[IDX_XCD_ + (xcd << 4)], 1u,
                           __ATOMIC_RELAXED, __HIP_MEMORY_SCOPE_AGENT);
    __hip_atomic_fetch_add(&p.cnt[IDX_INIT1_], 1u,
                           __ATOMIC_RELAXED, __HIP_MEMORY_SCOPE_AGENT);
    unsigned it = 0;
    while ((int)(__hip_atomic_load(&p.cnt[IDX_INIT1_], __ATOMIC_RELAXED,
                                   __HIP_MEMORY_SCOPE_AGENT) - NBLK_) < 0 &&
           ++it < POLL_CAP_)
      __builtin_amdgcn_s_sleep(1);
    nact = 0; nloc = 0;
    for (unsigned x = 0; x < 8; ++x) {
      unsigned c = __hip_atomic_load(&p.cnt[IDX_XCD_ + (x << 4)],
                                     __ATOMIC_RELAXED, __HIP_MEMORY_SCOPE_AGENT);
      if (c) ++nact;
      if (x == xcd) nloc = c;
    }
    // base of the never-reset local counter: RMW(+0) → L2-latest, bypasses L1
    lbase = __hip_atomic_fetch_add(&p.cnt[IDX_LCL_ + (xcd << 4)], 0u,
                                   __ATOMIC_RELAXED, __HIP_MEMORY_SCOPE_WORKGROUP);
    __hip_atomic_fetch_add(&p.cnt[IDX_INIT2_], 1u,
                           __ATOMIC_RELAXED, __HIP_MEMORY_SCOPE_AGENT);
    it = 0;
    while ((int)(__hip_atomic_load(&p.cnt[IDX_INIT2_], __ATOMIC_RELAXED,
                                   __HIP_MEMORY_SCOPE_AGENT) - NBLK_) < 0 &&
           ++it < POLL_CAP_)
      __builtin_amdgcn_s_sleep(1);
  }

  // ---- one-time: weights into registers ----
  // lane l supplies B-frag elems: B[k = s*32 + (l>>4)*8 + j][n = l&15]
  const int nIdx = lane & 15;
  const int ui = nIdx & 3, gate = nIdx >> 2;
  const int ko = (lane >> 4) * 8;
  f16x8 w[32];
  if (!isDyn) {
    const int r = gate * H_ + u0 + ui;
#pragma unroll
    for (int s = 0; s < 32; ++s) {
      const int k = s * 32 + ko;           // [0,256)=embN [256,512)=h_tensor [512,1024)=h
      const float* src = (k < 512) ? (p.W_ih + (size_t)r * 512 + k)
                                   : (p.W_hh + (size_t)r * 512 + (k - 512));
      f16x8 v;
#pragma unroll
      for (int j = 0; j < 8; ++j) v[j] = (f16)src[j];
      w[s] = v;
    }
  } else {
    const int r = gate * D_ + u0 + ui;
#pragma unroll
    for (int s = 0; s < 32; ++s) {
      const int k = s * 32 + ko;           // [0,256)=embN [256,768)=h [768,1024)=hd_prev
      const float* src = (k < 768) ? (p.Wd_ih + (size_t)r * 768 + k)
                                   : (p.Wd_hh + (size_t)r * 256 + (k - 768));
      f16x8 v;
#pragma unroll
      for (int j = 0; j < 8; ++j) v[j] = (f16)src[j];
      w[s] = v;
    }
  }
  if (tid < 16) {
    int g2 = tid >> 2, un2 = tid & 3;
    s_bias[tid] = isDyn ? (p.bd_ih[g2 * D_ + u0 + un2] + p.bd_hh[g2 * D_ + u0 + un2])
                        : (p.b_ih[g2 * H_ + u0 + un2] + p.b_hh[g2 * H_ + u0 + un2]);
  }
  float creg[4] = {0.f, 0.f, 0.f, 0.f};
  if (tid < 64 && !isDyn) {
#pragma unroll
    for (int un = 0; un < 4; ++un) creg[un] = p.cell_init[u0 + un];
  }
  if (tid < 64)
    resolve(p, isDyn, 0, tid, s_aN[0], s_aX[0], s_aC[0], s_dynw[0]);
  __syncthreads();

  for (int t = 0; t < T_; ++t) {
    const int pb = t & 1;

    // ---- prefetch cd_prev FIRST (overlaps with the A-load round trip) ----
    float4 cv;
    if (isDyn && tid < 64)
      cv = *(const float4*)(s_aC[pb][tid] + u0);

    // ---- gather A-frags (cached vector loads) + 32 MFMAs ----
    const int b = (wave << 4) + (lane & 15);
    const f16* pN = s_aN[pb][b];
    const f16* pX = s_aX[pb][b];
    const f16* pH = p.Hhist + ((size_t)t * B_ + b) * H_;
    f32x4 ac[4] = {{0,0,0,0},{0,0,0,0},{0,0,0,0},{0,0,0,0}};
    if (!isDyn) {
#pragma unroll
      for (int s = 0; s < 32; ++s) {
        f16x8 a;
        if (s < 8)       a = *(const f16x8*)(pN + s * 32 + ko);
        else if (s < 16) a = *(const f16x8*)(pX + (s - 8) * 32 + ko);
        else             a = *(const f16x8*)(pH + (s - 16) * 32 + ko);
        ac[s & 3] = __builtin_amdgcn_mfma_f32_16x16x32_f16(a, w[s], ac[s & 3], 0, 0, 0);
      }
    } else {
#pragma unroll
      for (int s = 0; s < 32; ++s) {
        f16x8 a;
        if (s < 8)       a = *(const f16x8*)(pN + s * 32 + ko);
        else if (s < 24) a = *(const f16x8*)(pH + (s - 8) * 32 + ko);
        else             a = *(const f16x8*)(pX + (s - 24) * 32 + ko);
        ac[s & 3] = __builtin_amdgcn_mfma_f32_16x16x32_f16(a, w[s], ac[s & 3], 0, 0, 0);
      }
    }
    f32x4 acc = (ac[0] + ac[1]) + (ac[2] + ac[3]);
    // D[m][n]: m = (lane>>4)*4 + j (batch in tile), n = lane&15 (gate row)
#pragma unroll
    for (int j = 0; j < 4; ++j)
      s_scr[(wave << 4) + ((lane >> 4) << 2) + j][lane & 15] = acc[j];
    __syncthreads();

    if (tid < 64) {
      // ---- epilogue: one batch per thread, 4 units (load-free) ----
      const int eb = tid;
      float g[16];
#pragma unroll
      for (int n = 0; n < 16; ++n) g[n] = s_scr[eb][n] + s_bias[n];
      if (!isDyn) {
        float4 ho;
        union { f16 h[4]; unsigned long long u; } pk;
#pragma unroll
        for (int un = 0; un < 4; ++un) {
          float c = sigm(g[4 + un]) * creg[un] + sigm(g[un]) * tanh_fast(g[8 + un]);
          creg[un] = c;
          float h = sigm(g[12 + un]) * tanh_fast(c);
          (&ho.x)[un] = h;
          pk.h[un] = (f16)h;
        }
        *(float4*)&p.out[((size_t)eb * T_ + t) * H_ + u0] = ho;
        cstore8(&p.Hhist[((size_t)(t + 1) * B_ + eb) * H_ + u0], pk.u);
      } else {
        const float cold[4] = {cv.x, cv.y, cv.z, cv.w};
        f32x4 co;
        union { f16 h[4]; unsigned long long u; } pk;
#pragma unroll
        for (int un = 0; un < 4; ++un) {
          float c = sigm(g[4 + un]) * cold[un] + sigm(g[un]) * tanh_fast(g[8 + un]);
          float h = sigm(g[12 + un]) * tanh_fast(c);
          pk.h[un] = (f16)h;
          co[un] = c;
        }
        if (s_dynw[pb][eb]) {
          cstore8(&p.HdHist[((size_t)t * B_ + eb) * D_ + u0], pk.u);
          cstore16(&p.CdHist[((size_t)t * B_ + eb) * D_ + u0], co);
        }
      }
    } else if (tid < 128 && t + 1 < T_) {
      // ---- wave 1: resolve next step's pointers concurrently ----
      resolve(p, isDyn, t + 1, tid - 64,
              s_aN[pb ^ 1], s_aX[pb ^ 1], s_aC[pb ^ 1], s_dynw[pb ^ 1]);
    }

    // ---- hierarchical barrier (skip after last step) ----
    if (t + 1 < T_) {
      __syncthreads();   // drains vmcnt: all block sc1 stores at the coherent point
      if (tid == 0) {
        const unsigned t1 = (unsigned)(t + 1);
        unsigned old = __hip_atomic_fetch_add(&p.cnt[IDX_LCL_ + (xcd << 4)], 1u,
                                              __ATOMIC_RELAXED,
                                              __HIP_MEMORY_SCOPE_WORKGROUP);
        if (old - lbase == nloc * t1 - 1u)   // last local arriver → global add
          __hip_atomic_fetch_add(&p.cnt[IDX_G_], 1u,
                                 __ATOMIC_RELAXED, __HIP_MEMORY_SCOPE_AGENT);
        const unsigned tgt = nact * t1;
        unsigned it = 0;
        while ((int)(__hip_atomic_load(&p.cnt[IDX_G_], __ATOMIC_RELAXED,
                                       __HIP_MEMORY_SCOPE_AGENT) - tgt) < 0 &&
               ++it < POLL_CAP_)
          __builtin_amdgcn_s_sleep(1);
      }
      __syncthreads();
    }
  }
}

extern "C" void kernel_launch(void* const* d_in, const int* in_sizes, int n_in,
                              void* d_out, int out_size, void* d_ws, size_t ws_size,
                              hipStream_t stream) {
  (void)in_sizes; (void)n_in; (void)out_size;
  const int* n_input   = (const int*)d_in[0];
  const int* t_input   = (const int*)d_in[1];
  const int* s2d       = (const int*)d_in[3];
  const float* embN    = (const float*)d_in[5];
  const float* embT    = (const float*)d_in[6];
  const float* W_ih    = (const float*)d_in[7];
  const float* W_hh    = (const float*)d_in[8];
  const float* b_ih    = (const float*)d_in[9];
  const float* b_hh    = (const float*)d_in[10];
  const float* Wd_ih   = (const float*)d_in[11];
  const float* Wd_hh   = (const float*)d_in[12];
  const float* bd_ih   = (const float*)d_in[13];
  const float* bd_hh   = (const float*)d_in[14];
  const float* hid_init  = (const float*)d_in[15];
  const float* cell_init = (const float*)d_in[16];
  const float* dyn_init_h = (const float*)d_in[17];
  const float* dyn_init_c = (const float*)d_in[18];

  char* ws = (char*)d_ws;
  unsigned* cnt  = (unsigned*)(ws + OFF_CNT);
  f16* embN16    = (f16*)(ws + OFF_EMBN);
  f16* embT16    = (f16*)(ws + OFF_EMBT);
  f16* dynih16   = (f16*)(ws + OFF_DINH);
  int* prev      = (int*)(ws + OFF_PREV);
  f16* Hhist     = (f16*)(ws + OFF_HH);
  f16* HdHist    = (f16*)(ws + OFF_HD);
  float* CdHist  = (float*)(ws + OFF_CD);
  if (ws_size < WS_NEED) return;

  setup_kernel<<<dim3((VN_ * EN_ + NTHR_ - 1) / NTHR_), dim3(NTHR_), 0, stream>>>(
      embN, embT, hid_init, dyn_init_h, embN16, embT16, dynih16, Hhist, cnt);
  prev_kernel<<<dim3((B_ * T_ + NTHR_ - 1) / NTHR_), dim3(NTHR_), 0, stream>>>(
      t_input, s2d, prev);

  RnnParams prm;
  prm.n_input = n_input; prm.t_input = t_input; prm.s2d = s2d;
  prm.W_ih = W_ih; prm.W_hh = W_hh; prm.b_ih = b_ih; prm.b_hh = b_hh;
  prm.Wd_ih = Wd_ih; prm.Wd_hh = Wd_hh; prm.bd_ih = bd_ih; prm.bd_hh = bd_hh;
  prm.cell_init = cell_init; prm.dyn_init_c = dyn_init_c;
  prm.embN16 = embN16; prm.embT16 = embT16; prm.dynih16 = dynih16;
  prm.prev = prev; prm.Hhist = Hhist; prm.HdHist = HdHist; prm.CdHist = CdHist;
  prm.out = (float*)d_out; prm.cnt = cnt;

  void* args[] = { &prm };
  hipError_t e = hipLaunchCooperativeKernel((const void*)rnn_main,
                                            dim3(NBLK_), dim3(NTHR_), args, 0, stream);
  if (e != hipSuccess) {
    rnn_main<<<dim3(NBLK_), dim3(NTHR_), 0, stream>>>(prm);
  }
}

// Round 6
// 1397.286 us; speedup vs baseline: 1.3654x; 1.3654x over previous
//
#include <hip/hip_runtime.h>

// DynamicRNNEncoder on MI355X — round 6.
// Persistent cooperative kernel; weights register-resident (f16).
// R4 flat 64-shard barrier + NEW: cross-barrier register prefetch of all
// step-independent A-slices (embN / embT / old-hd / old-cd); only Hhist[t]
// (+ rare pv==t-1 fixups) loads remain on the post-release critical path.

typedef _Float16 f16;
typedef _Float16 f16x8 __attribute__((ext_vector_type(8)));
typedef float f32x4 __attribute__((ext_vector_type(4)));

#define B_ 64
#define T_ 256
#define H_ 512
#define EN_ 256
#define ET_ 256
#define D_ 256
#define VN_ 300
#define VS_ 100

#define NB_MAIN_ 128   // 4 main units (16 gate rows) each
#define NB_DYN_ 64     // 4 dyn units each
#define NBLK_ 192
#define NTHR_ 256
#define NSH_ 64        // barrier counter shards (64B apart)
#define PER_SHARD_ (NBLK_ / NSH_)   // 3
#define POLL_CAP_ (1u << 22)

// ---- workspace layout (bytes) ----
static constexpr size_t OFF_CNT  = 0;                                   // 64 shards x 64B = 4KB
static constexpr size_t OFF_EMBN = 4096;                                // embN f16  [300][256]
static constexpr size_t OFF_EMBT = OFF_EMBN + (size_t)VN_ * EN_ * 2;    // embT f16  [100][256]
static constexpr size_t OFF_DINH = OFF_EMBT + (size_t)VS_ * ET_ * 2;    // dyn_init_h f16 [256]
static constexpr size_t OFF_PREV = OFF_DINH + 1024;                     // prev int32 [T][B]
static constexpr size_t OFF_HH   = OFF_PREV + (size_t)T_ * B_ * 4;      // Hhist f16 [T+1][B][H]
static constexpr size_t OFF_HD   = OFF_HH + (size_t)(T_ + 1) * B_ * H_ * 2; // HdHist f16 [T][B][D]
static constexpr size_t OFF_CD   = OFF_HD + (size_t)T_ * B_ * D_ * 2;   // CdHist f32 [T][B][D]
static constexpr size_t WS_NEED  = OFF_CD + (size_t)T_ * B_ * D_ * 4;   // ~42.3 MB

struct RnnParams {
  const int* n_input; const int* t_input; const int* s2d;
  const float* W_ih; const float* W_hh; const float* b_ih; const float* b_hh;
  const float* Wd_ih; const float* Wd_hh; const float* bd_ih; const float* bd_hh;
  const float* cell_init; const float* dyn_init_c;
  const f16* embN16; const f16* embT16; const f16* dynih16;
  const int* prev;
  f16* Hhist; f16* HdHist; float* CdHist;
  float* out; unsigned* cnt;
};

__device__ __forceinline__ float sigm(float x) { return 1.f / (1.f + __expf(-x)); }
__device__ __forceinline__ float tanh_fast(float x) {
  float e = __expf(2.f * x);
  return 1.f - 2.f / (e + 1.f);
}

// ---- coherent-point store helpers (sc0sc1 write-through) ----
__device__ __forceinline__ void cstore8(void* p, unsigned long long v) {
  __hip_atomic_store((unsigned long long*)p, v, __ATOMIC_RELAXED,
                     __HIP_MEMORY_SCOPE_AGENT);
}
__device__ __forceinline__ void cstore16(void* p, f32x4 v) {
  asm volatile("global_store_dwordx4 %0, %1, off sc0 sc1"
               :: "v"(p), "v"(v) : "memory");
}

// ---- setup: f16 conversions, Hhist[0] init, counter reset ----
__global__ void setup_kernel(const float* embN, const float* embT,
                             const float* hid_init, const float* dyn_init_h,
                             f16* embN16, f16* embT16, f16* dynih16,
                             f16* Hhist0, unsigned* cnt) {
  int i = blockIdx.x * blockDim.x + threadIdx.x;
  if (i < 1024)      cnt[i] = 0u;
  if (i < VN_ * EN_) embN16[i] = (f16)embN[i];
  if (i < VS_ * ET_) embT16[i] = (f16)embT[i];
  if (i < D_)        dynih16[i] = (f16)dyn_init_h[i];
  if (i < B_ * H_)   Hhist0[i] = (f16)hid_init[i & (H_ - 1)];
  __threadfence();
}

// ---- prev-occurrence table ----
__global__ void prev_kernel(const int* t_input, const int* s2d, int* prev) {
  int idx = blockIdx.x * blockDim.x + threadIdx.x;
  if (idx < B_ * T_) {
    int b = idx / T_, t = idx % T_;
    int tt = t_input[b * T_ + t];
    int p = -1;
    if (s2d[tt] != tt) {
      for (int q = t - 1; q >= 0; --q)
        if (t_input[b * T_ + q] == tt) { p = q; break; }
    }
    prev[t * B_ + b] = p;
  }
  __threadfence();
}

// resolve pointers for step t; tprev = t-1 (step whose stores may be in flight
// when we PREFETCH for step t) -> rc flags rows needing post-release reload.
__device__ __forceinline__ void resolve(const RnnParams& p, bool isDyn, int t, int b,
                                        int tprev,
                                        const f16** aN, const f16** aX,
                                        const float** aC, int* dynw, int* rc) {
  const int nt = p.n_input[b * T_ + t];
  aN[b] = p.embN16 + (size_t)nt * EN_;
  const int tt = p.t_input[b * T_ + t];
  const int pv = p.prev[t * B_ + b];
  rc[b] = (pv >= 0 && pv == tprev) ? 1 : 0;
  const f16* hd = (pv >= 0) ? (p.HdHist + ((size_t)pv * B_ + b) * D_) : p.dynih16;
  const int s2 = p.s2d[tt];
  const bool st = (s2 == tt);
  if (!isDyn) {
    aX[b] = st ? (p.embT16 + (size_t)s2 * ET_) : hd;
  } else {
    aX[b] = hd;
    aC[b] = (pv >= 0) ? (p.CdHist + ((size_t)pv * B_ + b) * D_) : p.dyn_init_c;
    dynw[b] = st ? 0 : 1;
  }
}

// ---- main cooperative recurrent kernel ----
__global__ __launch_bounds__(NTHR_, 1) void rnn_main(RnnParams p) {
  const int blk  = blockIdx.x;
  const int tid  = threadIdx.x;
  const int wave = tid >> 6;
  const int lane = tid & 63;
  const bool isDyn = (blk >= NB_MAIN_);
  const int u0 = isDyn ? (blk - NB_MAIN_) * 4 : blk * 4;

  __threadfence();   // one-time: invalidate caches to the coherent point

  __shared__ float s_bias[16];
  __shared__ float s_scr[64][17];
  __shared__ const f16*  s_aN[2][64];
  __shared__ const f16*  s_aX[2][64];
  __shared__ const float* s_aC[2][64];
  __shared__ int s_dynw[2][64];
  __shared__ int s_rc[2][64];

  // ---- one-time: weights into registers ----
  // lane l supplies B-frag elems: B[k = s*32 + (l>>4)*8 + j][n = l&15]
  const int nIdx = lane & 15;
  const int ui = nIdx & 3, gate = nIdx >> 2;
  const int ko = (lane >> 4) * 8;
  f16x8 w[32];
  if (!isDyn) {
    const int r = gate * H_ + u0 + ui;
#pragma unroll
    for (int s = 0; s < 32; ++s) {
      const int k = s * 32 + ko;           // [0,256)=embN [256,512)=h_tensor [512,1024)=h
      const float* src = (k < 512) ? (p.W_ih + (size_t)r * 512 + k)
                                   : (p.W_hh + (size_t)r * 512 + (k - 512));
      f16x8 v;
#pragma unroll
      for (int j = 0; j < 8; ++j) v[j] = (f16)src[j];
      w[s] = v;
    }
  } else {
    const int r = gate * D_ + u0 + ui;
#pragma unroll
    for (int s = 0; s < 32; ++s) {
      const int k = s * 32 + ko;           // [0,256)=embN [256,768)=h [768,1024)=hd_prev
      const float* src = (k < 768) ? (p.Wd_ih + (size_t)r * 768 + k)
                                   : (p.Wd_hh + (size_t)r * 256 + (k - 768));
      f16x8 v;
#pragma unroll
      for (int j = 0; j < 8; ++j) v[j] = (f16)src[j];
      w[s] = v;
    }
  }
  if (tid < 16) {
    int g2 = tid >> 2, un2 = tid & 3;
    s_bias[tid] = isDyn ? (p.bd_ih[g2 * D_ + u0 + un2] + p.bd_hh[g2 * D_ + u0 + un2])
                        : (p.b_ih[g2 * H_ + u0 + un2] + p.b_hh[g2 * H_ + u0 + un2]);
  }
  float creg[4] = {0.f, 0.f, 0.f, 0.f};
  if (tid < 64 && !isDyn) {
#pragma unroll
    for (int un = 0; un < 4; ++un) creg[un] = p.cell_init[u0 + un];
  }
  if (tid < 64)
    resolve(p, isDyn, 0, tid, -1, s_aN[0], s_aX[0], s_aC[0], s_dynw[0], s_rc[0]);
  __syncthreads();

  // ---- pre-loop prefetch for t=0 (all data already at coherent point) ----
  const int b = (wave << 4) + (lane & 15);
  f16x8 pf[16];      // [0..7]=embN slices, [8..15]=h_tensor/hd slices
  float4 cvp = {0.f, 0.f, 0.f, 0.f};
  {
    const f16* pN = s_aN[0][b];
    const f16* pX = s_aX[0][b];
#pragma unroll
    for (int i = 0; i < 8; ++i) pf[i] = *(const f16x8*)(pN + i * 32 + ko);
#pragma unroll
    for (int i = 0; i < 8; ++i) pf[8 + i] = *(const f16x8*)(pX + i * 32 + ko);
    if (isDyn && tid < 64) cvp = *(const float4*)(s_aC[0][tid] + u0);
  }

  for (int t = 0; t < T_; ++t) {
    const int pb = t & 1;

    // ---- post-release: Hhist[t] loads (the only step-critical loads) ----
    const f16* pH = p.Hhist + ((size_t)t * B_ + b) * H_;
    f16x8 hh[16];
#pragma unroll
    for (int i = 0; i < 16; ++i) hh[i] = *(const f16x8*)(pH + i * 32 + ko);
    // rare fixup: this batch's h_tensor/hd came from step t-1 (was in flight
    // when prefetched) -> reload now that the barrier guarantees visibility
    if (s_rc[pb][b]) {
      const f16* pX = s_aX[pb][b];
#pragma unroll
      for (int i = 0; i < 8; ++i) pf[8 + i] = *(const f16x8*)(pX + i * 32 + ko);
    }

    f32x4 ac[4] = {{0,0,0,0},{0,0,0,0},{0,0,0,0},{0,0,0,0}};
    if (!isDyn) {
#pragma unroll
      for (int i = 0; i < 8; ++i)
        ac[i & 3] = __builtin_amdgcn_mfma_f32_16x16x32_f16(pf[i], w[i], ac[i & 3], 0, 0, 0);
#pragma unroll
      for (int i = 0; i < 8; ++i)
        ac[i & 3] = __builtin_amdgcn_mfma_f32_16x16x32_f16(pf[8 + i], w[8 + i], ac[i & 3], 0, 0, 0);
#pragma unroll
      for (int i = 0; i < 16; ++i)
        ac[i & 3] = __builtin_amdgcn_mfma_f32_16x16x32_f16(hh[i], w[16 + i], ac[i & 3], 0, 0, 0);
    } else {
#pragma unroll
      for (int i = 0; i < 8; ++i)
        ac[i & 3] = __builtin_amdgcn_mfma_f32_16x16x32_f16(pf[i], w[i], ac[i & 3], 0, 0, 0);
#pragma unroll
      for (int i = 0; i < 8; ++i)
        ac[i & 3] = __builtin_amdgcn_mfma_f32_16x16x32_f16(pf[8 + i], w[24 + i], ac[i & 3], 0, 0, 0);
#pragma unroll
      for (int i = 0; i < 16; ++i)
        ac[i & 3] = __builtin_amdgcn_mfma_f32_16x16x32_f16(hh[i], w[8 + i], ac[i & 3], 0, 0, 0);
    }
    f32x4 acc = (ac[0] + ac[1]) + (ac[2] + ac[3]);
    // D[m][n]: m = (lane>>4)*4 + j (batch in tile), n = lane&15 (gate row)
#pragma unroll
    for (int j = 0; j < 4; ++j)
      s_scr[(wave << 4) + ((lane >> 4) << 2) + j][lane & 15] = acc[j];
    __syncthreads();

    if (tid < 64) {
      // ---- epilogue: one batch per thread, 4 units ----
      const int eb = tid;
      if (isDyn && s_rc[pb][eb])                       // rare cd fixup
        cvp = *(const float4*)(s_aC[pb][eb] + u0);
      float g[16];
#pragma unroll
      for (int n = 0; n < 16; ++n) g[n] = s_scr[eb][n] + s_bias[n];
      if (!isDyn) {
        float4 ho;
        union { f16 h[4]; unsigned long long u; } pk;
#pragma unroll
        for (int un = 0; un < 4; ++un) {
          float c = sigm(g[4 + un]) * creg[un] + sigm(g[un]) * tanh_fast(g[8 + un]);
          creg[un] = c;
          float h = sigm(g[12 + un]) * tanh_fast(c);
          (&ho.x)[un] = h;
          pk.h[un] = (f16)h;
        }
        *(float4*)&p.out[((size_t)eb * T_ + t) * H_ + u0] = ho;
        cstore8(&p.Hhist[((size_t)(t + 1) * B_ + eb) * H_ + u0], pk.u);
      } else {
        const float cold[4] = {cvp.x, cvp.y, cvp.z, cvp.w};
        f32x4 co;
        union { f16 h[4]; unsigned long long u; } pk;
#pragma unroll
        for (int un = 0; un < 4; ++un) {
          float c = sigm(g[4 + un]) * cold[un] + sigm(g[un]) * tanh_fast(g[8 + un]);
          float h = sigm(g[12 + un]) * tanh_fast(c);
          pk.h[un] = (f16)h;
          co[un] = c;
        }
        if (s_dynw[pb][eb]) {
          cstore8(&p.HdHist[((size_t)t * B_ + eb) * D_ + u0], pk.u);
          cstore16(&p.CdHist[((size_t)t * B_ + eb) * D_ + u0], co);
        }
      }
    } else if (tid < 128 && t + 1 < T_) {
      // ---- wave 1: resolve next step's pointers concurrently ----
      resolve(p, isDyn, t + 1, tid - 64, t,
              s_aN[pb ^ 1], s_aX[pb ^ 1], s_aC[pb ^ 1], s_dynw[pb ^ 1], s_rc[pb ^ 1]);
    }

    // ---- barrier with cross-barrier prefetch (skip after last step) ----
    if (t + 1 < T_) {
      __syncthreads();   // drains vmcnt: all sc1 stores at coherent point; resolve done
      if (tid == 0)
        __hip_atomic_fetch_add(&p.cnt[(blk & (NSH_ - 1)) << 4], 1u,
                               __ATOMIC_RELAXED, __HIP_MEMORY_SCOPE_AGENT);
      // prefetch step-independent slices for t+1: flies during the poll wait
      {
        const f16* pN2 = s_aN[pb ^ 1][b];
        const f16* pX2 = s_aX[pb ^ 1][b];
#pragma unroll
        for (int i = 0; i < 8; ++i) pf[i] = *(const f16x8*)(pN2 + i * 32 + ko);
#pragma unroll
        for (int i = 0; i < 8; ++i) pf[8 + i] = *(const f16x8*)(pX2 + i * 32 + ko);
        if (isDyn && tid < 64) cvp = *(const float4*)(s_aC[pb ^ 1][tid] + u0);
      }
      if (tid < NSH_) {
        const unsigned tgt = (unsigned)(t + 1) * PER_SHARD_;
        unsigned it = 0;
        while (__hip_atomic_load(&p.cnt[tid << 4], __ATOMIC_RELAXED,
                                 __HIP_MEMORY_SCOPE_AGENT) < tgt &&
               ++it < POLL_CAP_)
          __builtin_amdgcn_s_sleep(1);
      }
      __syncthreads();
    }
  }
}

extern "C" void kernel_launch(void* const* d_in, const int* in_sizes, int n_in,
                              void* d_out, int out_size, void* d_ws, size_t ws_size,
                              hipStream_t stream) {
  (void)in_sizes; (void)n_in; (void)out_size;
  const int* n_input   = (const int*)d_in[0];
  const int* t_input   = (const int*)d_in[1];
  const int* s2d       = (const int*)d_in[3];
  const float* embN    = (const float*)d_in[5];
  const float* embT    = (const float*)d_in[6];
  const float* W_ih    = (const float*)d_in[7];
  const float* W_hh    = (const float*)d_in[8];
  const float* b_ih    = (const float*)d_in[9];
  const float* b_hh    = (const float*)d_in[10];
  const float* Wd_ih   = (const float*)d_in[11];
  const float* Wd_hh   = (const float*)d_in[12];
  const float* bd_ih   = (const float*)d_in[13];
  const float* bd_hh   = (const float*)d_in[14];
  const float* hid_init  = (const float*)d_in[15];
  const float* cell_init = (const float*)d_in[16];
  const float* dyn_init_h = (const float*)d_in[17];
  const float* dyn_init_c = (const float*)d_in[18];

  char* ws = (char*)d_ws;
  unsigned* cnt  = (unsigned*)(ws + OFF_CNT);
  f16* embN16    = (f16*)(ws + OFF_EMBN);
  f16* embT16    = (f16*)(ws + OFF_EMBT);
  f16* dynih16   = (f16*)(ws + OFF_DINH);
  int* prev      = (int*)(ws + OFF_PREV);
  f16* Hhist     = (f16*)(ws + OFF_HH);
  f16* HdHist    = (f16*)(ws + OFF_HD);
  float* CdHist  = (float*)(ws + OFF_CD);
  if (ws_size < WS_NEED) return;

  setup_kernel<<<dim3((VN_ * EN_ + NTHR_ - 1) / NTHR_), dim3(NTHR_), 0, stream>>>(
      embN, embT, hid_init, dyn_init_h, embN16, embT16, dynih16, Hhist, cnt);
  prev_kernel<<<dim3((B_ * T_ + NTHR_ - 1) / NTHR_), dim3(NTHR_), 0, stream>>>(
      t_input, s2d, prev);

  RnnParams prm;
  prm.n_input = n_input; prm.t_input = t_input; prm.s2d = s2d;
  prm.W_ih = W_ih; prm.W_hh = W_hh; prm.b_ih = b_ih; prm.b_hh = b_hh;
  prm.Wd_ih = Wd_ih; prm.Wd_hh = Wd_hh; prm.bd_ih = bd_ih; prm.bd_hh = bd_hh;
  prm.cell_init = cell_init; prm.dyn_init_c = dyn_init_c;
  prm.embN16 = embN16; prm.embT16 = embT16; prm.dynih16 = dynih16;
  prm.prev = prev; prm.Hhist = Hhist; prm.HdHist = HdHist; prm.CdHist = CdHist;
  prm.out = (float*)d_out; prm.cnt = cnt;

  void* args[] = { &prm };
  hipError_t e = hipLaunchCooperativeKernel((const void*)rnn_main,
                                            dim3(NBLK_), dim3(NTHR_), args, 0, stream);
  if (e != hipSuccess) {
    rnn_main<<<dim3(NBLK_), dim3(NTHR_), 0, stream>>>(prm);
  }
}